// Round 2
// baseline (2630.325 us; speedup 1.0000x reference)
//
#include <hip/hip_runtime.h>
#include <math.h>

#define IN_DIM 128
#define HID    128
#define KDIM   256      // 2*IN_DIM
#define NN     100000
#define BM     32       // edges per block tile
#define BK     32       // K-chunk
#define NKC    (KDIM / BK)   // 8 chunks
#define WCHUNK (BK * HID)    // 4096 floats per W1 chunk

// Probe: edge_index may arrive as int32 or int64. If int64 (LE) with values
// < 2^31, every odd 32-bit word is 0. 64 consecutive real indices all being
// zero has probability ~0, so this is a reliable dtype detector.
__global__ void detect_idx64(const unsigned int* __restrict__ ei, int* __restrict__ flag) {
    unsigned v = ei[2 * threadIdx.x + 1];
    unsigned long long b = __ballot(v != 0u);
    if (threadIdx.x == 0) flag[0] = (b == 0ull) ? 1 : 0;
}

__global__ __launch_bounds__(256, 2)
void lp_decoder_main(const float* __restrict__ z,
                     const void* __restrict__ eidx,
                     const float* __restrict__ W1,
                     const float* __restrict__ b1,
                     const float* __restrict__ W2,
                     const float* __restrict__ b2,
                     float* __restrict__ out,
                     const int* __restrict__ flag,
                     int E)
{
    // XT[k][e]: gathered input, transposed so compute reads e-contiguous float4
    __shared__ float XT[KDIM][BM];        // 32 KB
    __shared__ float Ws[2][BK][HID];      // 32 KB double-buffered W1 chunks
    __shared__ float part[4][BM];         // cross-wave layer-2 partials

    const int t    = threadIdx.x;
    const int lane = t & 63;
    const int wave = t >> 6;
    const int e_sub = t & 31;             // staging: which edge this thread gathers
    const int q     = t >> 5;             // staging: which k-quad (0..7)
    const int eg = lane & 7;              // compute: edge group (4 edges)
    const int jg = (wave << 3) | (lane >> 3);  // compute: hidden group (4 j), 0..31

    const int e0 = blockIdx.x * BM;
    const int use64 = flag[0];

    // ---- edge indices for this thread's staging edge ----
    int s_node, d_node;
    {
        int e = e0 + e_sub;
        if (e > E - 1) e = E - 1;
        if (use64) {
            const long long* p = (const long long*)eidx;
            s_node = (int)p[e];
            d_node = (int)p[(long long)E + e];
        } else {
            const int* p = (const int*)eidx;
            s_node = p[e];
            d_node = p[E + e];
        }
        s_node = min(max(s_node, 0), NN - 1);   // defensive clamp (no OOB fault)
        d_node = min(max(d_node, 0), NN - 1);
    }

    // ---- stage XT: XT[k][e] = (k<128 ? z[src][k] : z[dst][k-128]) ----
    // thread (q, e_sub) loads float4 at k = r*32 + q*4, writes 4 scalar LDS
    // words (2-way bank aliasing across the wave halves = free per m136).
    #pragma unroll
    for (int r = 0; r < 8; ++r) {
        const int kb = r * 32 + q * 4;
        const int node = (kb < IN_DIM) ? s_node : d_node;
        const int col  = kb & (IN_DIM - 1);
        const float4 v = *reinterpret_cast<const float4*>(&z[node * IN_DIM + col]);
        XT[kb + 0][e_sub] = v.x;
        XT[kb + 1][e_sub] = v.y;
        XT[kb + 2][e_sub] = v.z;
        XT[kb + 3][e_sub] = v.w;
    }

    // ---- stage W chunk 0: 4096 floats = 256 threads x 4 float4 ----
    #pragma unroll
    for (int i = 0; i < 4; ++i) {
        const float4 wv = *reinterpret_cast<const float4*>(&W1[i * 1024 + t * 4]);
        *reinterpret_cast<float4*>(&Ws[0][0][0] + i * 1024 + t * 4) = wv;
    }
    __syncthreads();

    float acc[4][4] = {{0.f, 0.f, 0.f, 0.f}};

    // ---- K loop: double-buffered W chunks, 16 FMA per 2 ds_read_b128 ----
    for (int kc = 0; kc < NKC; ++kc) {
        const int buf = kc & 1;
        float4 wpre[4];
        const bool pre = (kc + 1 < NKC);
        if (pre) {  // issue global loads early; they hide under the 512-FMA block
            #pragma unroll
            for (int i = 0; i < 4; ++i)
                wpre[i] = *reinterpret_cast<const float4*>(
                    &W1[(kc + 1) * WCHUNK + i * 1024 + t * 4]);
        }

        #pragma unroll
        for (int kk = 0; kk < BK; ++kk) {
            const float4 xv = *reinterpret_cast<const float4*>(&XT[kc * BK + kk][eg * 4]);
            const float4 wv = *reinterpret_cast<const float4*>(&Ws[buf][kk][jg * 4]);
            const float xs[4]  = {xv.x, xv.y, xv.z, xv.w};
            const float ws4[4] = {wv.x, wv.y, wv.z, wv.w};
            #pragma unroll
            for (int i = 0; i < 4; ++i)
                #pragma unroll
                for (int j = 0; j < 4; ++j)
                    acc[i][j] = fmaf(xs[i], ws4[j], acc[i][j]);
        }
        // Writing buf^1 is safe: its last readers finished before the barrier
        // that ended iteration kc-1. Single barrier per iteration.
        if (pre) {
            #pragma unroll
            for (int i = 0; i < 4; ++i)
                *reinterpret_cast<float4*>(&Ws[buf ^ 1][0][0] + i * 1024 + t * 4) = wpre[i];
        }
        __syncthreads();
    }

    // ---- fused layer 2: relu(acc + b1) . W2, reduce over j ----
    const float4 b1v = *reinterpret_cast<const float4*>(&b1[jg * 4]);
    const float4 w2v = *reinterpret_cast<const float4*>(&W2[jg * 4]);
    float p[4];
    #pragma unroll
    for (int i = 0; i < 4; ++i) {
        const float h0 = fmaxf(acc[i][0] + b1v.x, 0.f);
        const float h1 = fmaxf(acc[i][1] + b1v.y, 0.f);
        const float h2 = fmaxf(acc[i][2] + b1v.z, 0.f);
        const float h3 = fmaxf(acc[i][3] + b1v.w, 0.f);
        p[i] = h0 * w2v.x + h1 * w2v.y + h2 * w2v.z + h3 * w2v.w;
    }
    // in-wave reduce across the 8 j-groups (lane bits 3..5)
    #pragma unroll
    for (int off = 8; off <= 32; off <<= 1) {
        #pragma unroll
        for (int i = 0; i < 4; ++i)
            p[i] += __shfl_xor(p[i], off);
    }
    if ((lane >> 3) == 0) {
        #pragma unroll
        for (int i = 0; i < 4; ++i)
            part[wave][eg * 4 + i] = p[i];
    }
    __syncthreads();
    if (t < BM) {
        const int e = e0 + t;
        if (e < E) {
            const float s = part[0][t] + part[1][t] + part[2][t] + part[3][t] + b2[0];
            out[e] = 1.f / (1.f + expf(-s));
        }
    }
}

extern "C" void kernel_launch(void* const* d_in, const int* in_sizes, int n_in,
                              void* d_out, int out_size, void* d_ws, size_t ws_size,
                              hipStream_t stream) {
    const float* z  = (const float*)d_in[0];
    const void*  ei = d_in[1];
    const float* W1 = (const float*)d_in[2];
    const float* b1 = (const float*)d_in[3];
    const float* W2 = (const float*)d_in[4];
    const float* b2 = (const float*)d_in[5];
    float* out = (float*)d_out;
    int* flag  = (int*)d_ws;

    const int E = in_sizes[1] / 2;   // edge_index is [2][E]

    hipLaunchKernelGGL(detect_idx64, dim3(1), dim3(64), 0, stream,
                       (const unsigned int*)ei, flag);

    const int tiles = (E + BM - 1) / BM;
    hipLaunchKernelGGL(lp_decoder_main, dim3(tiles), dim3(256), 0, stream,
                       z, ei, W1, b1, W2, b2, out, flag, E);
}

// Round 3
// 246.380 us; speedup vs baseline: 10.6759x; 10.6759x over previous
//
#include <hip/hip_runtime.h>
#include <math.h>

#define IN_DIM 128
#define HID    128
#define KDIM   256         // 2*IN_DIM
#define NN     100000
#define BM     64          // edges per block tile
#define WPACK_BYTES (8 * 8 * 64 * 16)   // 8 kc x 8 jsg x 64 lanes x 16B = 64 KB
#define WPACK_OFF   64                   // wpack offset inside d_ws (flag at 0)

typedef __attribute__((ext_vector_type(8))) __bf16 bf16x8;
typedef __attribute__((ext_vector_type(4))) float  f32x4;

__device__ __forceinline__ unsigned f2bf(float f) {
    unsigned u = __float_as_uint(f);
    return (u + 0x7FFFu + ((u >> 16) & 1u)) >> 16;   // RTN-even
}

// Probe: edge_index may arrive as int32 or int64. If int64 (LE) with values
// < 2^31, every odd 32-bit word is 0 across 64 consecutive indices.
__global__ void detect_idx64(const unsigned int* __restrict__ ei, int* __restrict__ flag) {
    unsigned v = ei[2 * threadIdx.x + 1];
    unsigned long long b = __ballot(v != 0u);
    if (threadIdx.x == 0) flag[0] = (b == 0ull) ? 1 : 0;
}

// Pack W1 (fp32 [256][128]) into per-lane bf16 MFMA B-fragments.
// Fragment (kc, jsg): lane l holds B[k = kc*32 + (l>>4)*8 + 0..7][j = jsg*16 + (l&15)]
// as 8 bf16 = one uint4.
__global__ void pack_w1(const float* __restrict__ W1, uint4* __restrict__ wpack) {
    const int t = threadIdx.x;
    const int lane = t & 63;
    #pragma unroll
    for (int fi = 0; fi < 16; ++fi) {
        const int frag = (t >> 6) + fi * 4;       // 0..63
        const int kc  = frag >> 3;
        const int jsg = frag & 7;
        const int k0  = kc * 32 + ((lane >> 4) * 8);
        const int j   = jsg * 16 + (lane & 15);
        unsigned wv[4];
        #pragma unroll
        for (int p = 0; p < 4; ++p) {
            const unsigned lo = f2bf(W1[(k0 + 2 * p)     * HID + j]);
            const unsigned hi = f2bf(W1[(k0 + 2 * p + 1) * HID + j]);
            wv[p] = lo | (hi << 16);
        }
        wpack[frag * 64 + lane] = make_uint4(wv[0], wv[1], wv[2], wv[3]);
    }
}

__global__ __launch_bounds__(256, 3)
void lp_decoder_mfma(const float* __restrict__ z,
                     const void* __restrict__ eidx,
                     const float* __restrict__ W1,
                     const float* __restrict__ b1,
                     const float* __restrict__ W2,
                     const float* __restrict__ b2,
                     float* __restrict__ out,
                     const int* __restrict__ flag,
                     const uint4* __restrict__ wpack,
                     int use_ws, int E)
{
    // A-tile: BM rows x 256 bf16 (512 B/row), XOR-swizzled: byte ^= (row&7)<<4.
    __shared__ uint4 ldsA_[BM * 512 / 16];      // 32 KB
    __shared__ float part[4][BM];               // 1 KB cross-wave L2-partials
    char* ldsc = (char*)ldsA_;

    const int t    = threadIdx.x;
    const int lane = t & 63;
    const int w    = t >> 6;
    const int e0   = blockIdx.x * BM;
    const int use64 = flag[0];

    // ---- B fragments: 16 per wave (8 k-chunks x 2 j-subtiles), kept in VGPRs ----
    bf16x8 Bf[8][2];
    if (use_ws) {
        #pragma unroll
        for (int kc = 0; kc < 8; ++kc)
            #pragma unroll
            for (int js = 0; js < 2; ++js)
                Bf[kc][js] = __builtin_bit_cast(bf16x8,
                    wpack[(kc * 8 + (w * 2 + js)) * 64 + lane]);
    } else {
        #pragma unroll
        for (int kc = 0; kc < 8; ++kc)
            #pragma unroll
            for (int js = 0; js < 2; ++js) {
                const int k0 = kc * 32 + ((lane >> 4) * 8);
                const int j  = (w * 2 + js) * 16 + (lane & 15);
                unsigned wv[4];
                #pragma unroll
                for (int p = 0; p < 4; ++p) {
                    const unsigned lo = f2bf(W1[(k0 + 2 * p)     * HID + j]);
                    const unsigned hi = f2bf(W1[(k0 + 2 * p + 1) * HID + j]);
                    wv[p] = lo | (hi << 16);
                }
                Bf[kc][js] = __builtin_bit_cast(bf16x8, make_uint4(wv[0], wv[1], wv[2], wv[3]));
            }
    }

    // ---- gather-convert stage: wave w stages edge el = i*4 + w each iter ----
    // lane = 8B k-slot (k = lane*4); lanes 0..31 = src row, 32..63 = dst row.
    #pragma unroll 4
    for (int i = 0; i < 16; ++i) {
        const int el = i * 4 + w;
        int e = e0 + el;
        if (e > E - 1) e = E - 1;
        int node;
        if (use64) {
            const long long* p = (const long long*)eidx;
            node = (int)((lane < 32) ? p[e] : p[(long long)E + e]);
        } else {
            const int* p = (const int*)eidx;
            node = (lane < 32) ? p[e] : p[E + e];
        }
        node = min(max(node, 0), NN - 1);
        const float4 v = *reinterpret_cast<const float4*>(&z[node * IN_DIM + (lane & 31) * 4]);
        const unsigned lo = f2bf(v.x) | (f2bf(v.y) << 16);
        const unsigned hi = f2bf(v.z) | (f2bf(v.w) << 16);
        const int byte = el * 512 + ((lane * 8) ^ ((el & 7) << 4));
        *reinterpret_cast<uint2*>(ldsc + byte) = make_uint2(lo, hi);
    }
    __syncthreads();

    // ---- K loop: pure LDS-read + MFMA, no barriers ----
    f32x4 acc[4][2] = {};
    const int e_r  = (lane & 15);                 // row-in-subtile
    const int m16  = (lane >> 4) * 16;            // k-octet byte offset
    #pragma unroll
    for (int kc = 0; kc < 8; ++kc) {
        #pragma unroll
        for (int es = 0; es < 4; ++es) {
            const int row  = es * 16 + e_r;
            const int byte = row * 512 + ((kc * 64 + m16) ^ ((row & 7) << 4));
            const bf16x8 a = *reinterpret_cast<const bf16x8*>(ldsc + byte);
            acc[es][0] = __builtin_amdgcn_mfma_f32_16x16x32_bf16(a, Bf[kc][0], acc[es][0], 0, 0, 0);
            acc[es][1] = __builtin_amdgcn_mfma_f32_16x16x32_bf16(a, Bf[kc][1], acc[es][1], 0, 0, 0);
        }
    }

    // ---- fused layer 2: relu(acc + b1) . W2 ----
    // D layout: col j = jbase + js*16 + (lane&15); row e = es*16 + (lane>>4)*4 + reg
    const int jb = w * 32 + (lane & 15);
    const float b1v[2] = { b1[jb], b1[jb + 16] };
    const float w2v[2] = { W2[jb], W2[jb + 16] };
    float p[4][4];
    #pragma unroll
    for (int es = 0; es < 4; ++es)
        #pragma unroll
        for (int reg = 0; reg < 4; ++reg) {
            float s = 0.f;
            #pragma unroll
            for (int js = 0; js < 2; ++js)
                s += fmaxf(acc[es][js][reg] + b1v[js], 0.f) * w2v[js];
            p[es][reg] = s;
        }
    #pragma unroll
    for (int off = 1; off <= 8; off <<= 1)
        #pragma unroll
        for (int es = 0; es < 4; ++es)
            #pragma unroll
            for (int reg = 0; reg < 4; ++reg)
                p[es][reg] += __shfl_xor(p[es][reg], off);
    if ((lane & 15) == 0) {
        const int m = lane >> 4;
        #pragma unroll
        for (int es = 0; es < 4; ++es)
            #pragma unroll
            for (int reg = 0; reg < 4; ++reg)
                part[w][es * 16 + m * 4 + reg] = p[es][reg];
    }
    __syncthreads();
    if (t < BM) {
        const int e = e0 + t;
        if (e < E) {
            const float s = part[0][t] + part[1][t] + part[2][t] + part[3][t] + b2[0];
            out[e] = 1.f / (1.f + expf(-s));
        }
    }
}

extern "C" void kernel_launch(void* const* d_in, const int* in_sizes, int n_in,
                              void* d_out, int out_size, void* d_ws, size_t ws_size,
                              hipStream_t stream) {
    const float* z  = (const float*)d_in[0];
    const void*  ei = d_in[1];
    const float* W1 = (const float*)d_in[2];
    const float* b1 = (const float*)d_in[3];
    const float* W2 = (const float*)d_in[4];
    const float* b2 = (const float*)d_in[5];
    float* out = (float*)d_out;
    int*   flag  = (int*)d_ws;
    uint4* wpack = (uint4*)((char*)d_ws + WPACK_OFF);

    const int E = in_sizes[1] / 2;   // edge_index is [2][E]
    const int use_ws = (ws_size >= (size_t)(WPACK_OFF + WPACK_BYTES)) ? 1 : 0;

    hipLaunchKernelGGL(detect_idx64, dim3(1), dim3(64), 0, stream,
                       (const unsigned int*)ei, flag);
    if (use_ws)
        hipLaunchKernelGGL(pack_w1, dim3(1), dim3(256), 0, stream, W1, wpack);

    const int tiles = (E + BM - 1) / BM;
    hipLaunchKernelGGL(lp_decoder_mfma, dim3(tiles), dim3(256), 0, stream,
                       z, ei, W1, b1, W2, b2, out, flag, wpack, use_ws, E);
}

// Round 5
// 144.440 us; speedup vs baseline: 18.2105x; 1.7058x over previous
//
#include <hip/hip_runtime.h>
#include <math.h>

#define IN_DIM 128
#define HID    128
#define NN     100000
#define BM     64                        // edges per tile
#define GRID_BLOCKS 768                  // 3 blocks/CU * 256 CU (persistent)
#define WFRAGS 64                        // 8 kc x 8 jsg
#define WPACK_BYTES (WFRAGS * 64 * 16)   // 64 KB
#define WPACK_OFF   64                   // wpack offset in d_ws (flag at 0)

typedef __attribute__((ext_vector_type(8))) __bf16 bf16x8;
typedef __attribute__((ext_vector_type(4))) float  f32x4;

__device__ __forceinline__ unsigned pk2bf(float a, float b) {
    union { __bf16 h[2]; unsigned u; } r;
    r.h[0] = (__bf16)a; r.h[1] = (__bf16)b;   // compiler fuses to v_cvt_pk_bf16_f32
    return r.u;
}

// One prep kernel: dtype probe (int64 indices < 2^31 have all-zero odd words)
// + W1 fp32 -> per-lane bf16 MFMA B-fragment packing into d_ws.
__global__ void prep(const float* __restrict__ W1,
                     const unsigned* __restrict__ ei,
                     uint4* __restrict__ wpack,
                     int* __restrict__ flag, int do_pack) {
    const int t = threadIdx.x;
    if (t < 64) {
        unsigned v = ei[2 * t + 1];
        unsigned long long b = __ballot(v != 0u);
        if (t == 0) flag[0] = (b == 0ull) ? 1 : 0;
    }
    if (!do_pack) return;
    const int lane = t & 63;
    #pragma unroll
    for (int fi = 0; fi < 16; ++fi) {
        const int frag = (t >> 6) + fi * 4;          // 0..63
        const int kc = frag >> 3, jsg = frag & 7;
        const int k0 = kc * 32 + (lane >> 4) * 8;
        const int j  = jsg * 16 + (lane & 15);
        unsigned wv[4];
        #pragma unroll
        for (int p = 0; p < 4; ++p)
            wv[p] = pk2bf(W1[(k0 + 2 * p) * HID + j], W1[(k0 + 2 * p + 1) * HID + j]);
        wpack[frag * 64 + lane] = make_uint4(wv[0], wv[1], wv[2], wv[3]);
    }
}

__global__ __launch_bounds__(256, 3)
void lp_main(const float* __restrict__ z,
             const int* __restrict__ ei32,
             const float* __restrict__ W1,
             const float* __restrict__ b1,
             const float* __restrict__ W2,
             const float* __restrict__ b2,
             float* __restrict__ out,
             const int* __restrict__ flag,
             const uint4* __restrict__ wpack,
             int use_ws, int E, int ntiles)
{
    // A-tile: BM rows x 256 bf16 (512 B/row), XOR-swizzled: byte ^= (row&7)<<4.
    __shared__ uint4 ldsA_[BM * 512 / 16];      // 32 KB, single-buffered
    __shared__ float part[4][BM];               // cross-wave layer-2 partials
    char* ldsc = (char*)ldsA_;

    const int t    = threadIdx.x;
    const int lane = t & 63;
    const int w    = t >> 6;
    const int use64 = flag[0];                  // wave-uniform

    // ---- B fragments: 16 per wave, loaded ONCE, pinned resident ----
    uint4 Bf[8][2];
    if (use_ws) {
        #pragma unroll
        for (int kc = 0; kc < 8; ++kc)
            #pragma unroll
            for (int js = 0; js < 2; ++js)
                Bf[kc][js] = wpack[(kc * 8 + (w * 2 + js)) * 64 + lane];
    } else {
        #pragma unroll
        for (int kc = 0; kc < 8; ++kc)
            #pragma unroll
            for (int js = 0; js < 2; ++js) {
                const int k0 = kc * 32 + (lane >> 4) * 8;
                const int j  = (w * 2 + js) * 16 + (lane & 15);
                unsigned wv[4];
                #pragma unroll
                for (int p = 0; p < 4; ++p)
                    wv[p] = pk2bf(W1[(k0 + 2 * p) * HID + j],
                                  W1[(k0 + 2 * p + 1) * HID + j]);
                Bf[kc][js] = make_uint4(wv[0], wv[1], wv[2], wv[3]);
            }
    }
    // Keep Bf live across the tile loop (R3's VGPR=56 showed the compiler
    // sinking these loads to their uses). Pin per 32-bit component — tied
    // constraints on whole uint4 vectors are unsupported (R4 compile error).
    #pragma unroll
    for (int kc = 0; kc < 8; ++kc)
        #pragma unroll
        for (int js = 0; js < 2; ++js)
            asm volatile("" : "+v"(Bf[kc][js].x), "+v"(Bf[kc][js].y),
                              "+v"(Bf[kc][js].z), "+v"(Bf[kc][js].w));

    const int e_r = lane & 15;
    const int q   = lane >> 4;
    const int m16 = q * 16;
    const float b1v0 = b1[w * 32 + e_r],      b1v1 = b1[w * 32 + 16 + e_r];
    const float w2v0 = W2[w * 32 + e_r],      w2v1 = W2[w * 32 + 16 + e_r];
    const float b2v  = b2[0];

    for (int tile = blockIdx.x; tile < ntiles; tile += gridDim.x) {
        const int e0 = tile * BM;

        // ---- stage A-tile: gather + convert; wave w stages rows i*4+w ----
        #pragma unroll 8
        for (int i = 0; i < 16; ++i) {
            const int el = i * 4 + w;
            int e = e0 + el; if (e > E - 1) e = E - 1;
            const int word = (lane < 32) ? e : (E + e);
            int node = ei32[(long long)word << use64];   // int32 or lo-word of int64
            node = min(max(node, 0), NN - 1);
            const float4 v = *reinterpret_cast<const float4*>(
                &z[node * IN_DIM + (lane & 31) * 4]);
            const int byte = el * 512 + ((lane * 8) ^ ((el & 7) << 4));
            *reinterpret_cast<uint2*>(ldsc + byte) =
                make_uint2(pk2bf(v.x, v.y), pk2bf(v.z, v.w));
        }
        __syncthreads();

        // ---- K loop: 32 ds_read_b128 + 64 MFMA per wave ----
        f32x4 acc[4][2] = {};
        #pragma unroll
        for (int kc = 0; kc < 8; ++kc) {
            #pragma unroll
            for (int es = 0; es < 4; ++es) {
                const int row  = es * 16 + e_r;
                const int byte = row * 512 + ((kc * 64 + m16) ^ ((row & 7) << 4));
                const bf16x8 a = *reinterpret_cast<const bf16x8*>(ldsc + byte);
                acc[es][0] = __builtin_amdgcn_mfma_f32_16x16x32_bf16(
                    a, __builtin_bit_cast(bf16x8, Bf[kc][0]), acc[es][0], 0, 0, 0);
                acc[es][1] = __builtin_amdgcn_mfma_f32_16x16x32_bf16(
                    a, __builtin_bit_cast(bf16x8, Bf[kc][1]), acc[es][1], 0, 0, 0);
            }
        }

        // ---- fused layer 2: relu(acc+b1).W2, distribute-reduce over 16 j-lanes ----
        float v16[16];
        #pragma unroll
        for (int es = 0; es < 4; ++es)
            #pragma unroll
            for (int reg = 0; reg < 4; ++reg)
                v16[es * 4 + reg] = fmaxf(acc[es][0][reg] + b1v0, 0.f) * w2v0
                                  + fmaxf(acc[es][1][reg] + b1v1, 0.f) * w2v1;
        // 15 shuffles total; after round r, lane bit r selects which half survives
        #pragma unroll
        for (int rnd = 0; rnd < 4; ++rnd) {
            const int o = 1 << rnd;
            const int half = 8 >> rnd;
            #pragma unroll
            for (int i = 0; i < half; ++i) {
                const float a = v16[i], b = v16[i + half];
                const float s = (lane & o) ? a : b;     // send the one I don't keep
                const float r = __shfl_xor(s, o);
                v16[i] = ((lane & o) ? b : a) + r;
            }
        }
        // lane (q,l4) now holds edge (es,reg) = bitrev4(l4), fully reduced
        {
            const int l4  = lane & 15;
            const int idx = ((l4 & 1) << 3) | ((l4 & 2) << 1) | ((l4 & 4) >> 1) | ((l4 & 8) >> 3);
            const int edge = (idx >> 2) * 16 + q * 4 + (idx & 3);
            part[w][edge] = v16[0];
        }
        __syncthreads();

        if (t < BM) {
            const int e = e0 + t;
            if (e < E) {
                const float s = part[0][t] + part[1][t] + part[2][t] + part[3][t] + b2v;
                out[e] = 1.f / (1.f + expf(-s));
            }
        }
        // next iteration's A-tile writes are fenced from this tile's reads by
        // the staging->MFMA barrier; part writes of tile t+1 happen after that
        // barrier, which wave 0 only reaches after reading part(t).
    }
}

extern "C" void kernel_launch(void* const* d_in, const int* in_sizes, int n_in,
                              void* d_out, int out_size, void* d_ws, size_t ws_size,
                              hipStream_t stream) {
    const float* z  = (const float*)d_in[0];
    const void*  ei = d_in[1];
    const float* W1 = (const float*)d_in[2];
    const float* b1 = (const float*)d_in[3];
    const float* W2 = (const float*)d_in[4];
    const float* b2 = (const float*)d_in[5];
    float* out = (float*)d_out;
    int*   flag  = (int*)d_ws;
    uint4* wpack = (uint4*)((char*)d_ws + WPACK_OFF);

    const int E = in_sizes[1] / 2;   // edge_index is [2][E]
    const int use_ws = (ws_size >= (size_t)(WPACK_OFF + WPACK_BYTES)) ? 1 : 0;

    hipLaunchKernelGGL(prep, dim3(1), dim3(256), 0, stream,
                       W1, (const unsigned*)ei, wpack, flag, use_ws);

    const int ntiles = (E + BM - 1) / BM;
    const int grid = (ntiles < GRID_BLOCKS) ? ntiles : GRID_BLOCKS;
    hipLaunchKernelGGL(lp_main, dim3(grid), dim3(256), 0, stream,
                       z, (const int*)ei, W1, b1, W2, b2, out, flag, wpack, use_ws, E, ntiles);
}